// Round 5
// baseline (297.948 us; speedup 1.0000x reference)
//
#include <hip/hip_runtime.h>
#include <hip/hip_bf16.h>

#define BB 256
#define PP 48
#define NN 64
#define EPSBN 1e-5f

typedef __attribute__((ext_vector_type(8))) short bf16x8;
typedef __attribute__((ext_vector_type(4))) float f32x4;

// ---- LDS regions (ushort offsets), total 81920 ushorts = 163840 B (160 KiB) ----
#define BIGO 0       // 32768: fr1R/[+16384]fr1S -> fr2 [128][256]   | N: fo1 [256][128] -> fo2 [128][256]
#define S1SO 32768   // 16384: S1S [64][256]                          | N: act1N [64][256]
#define S1RO 49152   // 16384: S1R [64][256]; part/ebar cols 0..63    | N: fo3 [64][128]
#define F3LO 65536   //  8192: phase E: fr3 [64][128]                 | N: act2N [64][128]
#define A2WO 73728   //  8192: phase E: 8 waves x 1024 ([16][64])     | N: red/h1/h2 floats @73728
#define REDO 73728
#define XNTP 77824   //  4096: xnT [64][64] (prologue + phase N restage; clobbered by waves 4..7 a2w)
#define LDSE 81920

union U8 { bf16x8 v; unsigned u[4]; };

__device__ __forceinline__ unsigned pku(float a, float b) {
    union { __hip_bfloat162 h; unsigned u; } cv;
    cv.h = __float22bfloat162_rn(make_float2(a, b));
    return cv.u;
}
__device__ __forceinline__ ushort f2b(float f) {
    union { float f; unsigned u; } a; a.f = f;
    unsigned u = a.u + 0x7FFFu + ((a.u >> 16) & 1u);
    return (ushort)(u >> 16);
}
__device__ __forceinline__ float loF(unsigned u) { union { unsigned x; float f; } c; c.x = u << 16; return c.f; }
__device__ __forceinline__ float hiF(unsigned u) { union { unsigned x; float f; } c; c.x = u & 0xffff0000u; return c.f; }

__device__ __forceinline__ int sidx(int row, int k, int kpad) {
    return row * kpad + ((((k >> 3) ^ (row & 7)) << 3) | (k & 7));
}
__device__ __forceinline__ bf16x8 ldfrag(const ushort* buf, int row, int k, int kpad) {
    return *(const bf16x8*)(buf + row * kpad + (((k >> 3) ^ (row & 7)) << 3));
}
__device__ __forceinline__ f32x4 MFMA(bf16x8 a, bf16x8 b, f32x4 c) {
    return __builtin_amdgcn_mfma_f32_16x16x32_bf16(a, b, c, 0, 0, 0);
}
__device__ __forceinline__ void stAct(ushort* buf, int row, int c0, int kpad, f32x4 a, float4 bi) {
    uint2 o;
    o.x = pku(fmaxf(a[0] + bi.x, 0.f), fmaxf(a[1] + bi.y, 0.f));
    o.y = pku(fmaxf(a[2] + bi.z, 0.f), fmaxf(a[3] + bi.w, 0.f));
    *(uint2*)(buf + row * kpad + ((((c0 >> 3) ^ (row & 7)) << 3) | (c0 & 7))) = o;
}
// bias folded into accumulator init: store relu(acc) only
__device__ __forceinline__ void stAct0(ushort* buf, int row, int c0, int kpad, f32x4 a) {
    uint2 o;
    o.x = pku(fmaxf(a[0], 0.f), fmaxf(a[1], 0.f));
    o.y = pku(fmaxf(a[2], 0.f), fmaxf(a[3], 0.f));
    *(uint2*)(buf + row * kpad + ((((c0 >> 3) ^ (row & 7)) << 3) | (c0 & 7))) = o;
}
__device__ __forceinline__ void stRaw(ushort* buf, int row, int c0, int kpad, f32x4 a, float4 bi) {
    uint2 o;
    o.x = pku(a[0] + bi.x, a[1] + bi.y);
    o.y = pku(a[2] + bi.z, a[3] + bi.w);
    *(uint2*)(buf + row * kpad + ((((c0 >> 3) ^ (row & 7)) << 3) | (c0 & 7))) = o;
}

// ---------------- batchnorm stats ----------------
__global__ __launch_bounds__(256) void bn_stats_kernel(
    const float* __restrict__ x, const float* __restrict__ gamma,
    const float* __restrict__ beta, float* __restrict__ scale, float* __restrict__ bias)
{
    __shared__ float s_sum[256], s_sq[256];
    int p = blockIdx.x, t = threadIdx.x;
    float sum = 0.f, sq = 0.f;
    for (int i = t; i < BB * NN; i += 256) {
        int b = i >> 6, n = i & 63;
        float v = x[b * PP * NN + p * NN + n];
        sum += v; sq += v * v;
    }
    s_sum[t] = sum; s_sq[t] = sq;
    __syncthreads();
    for (int off = 128; off > 0; off >>= 1) {
        if (t < off) { s_sum[t] += s_sum[t + off]; s_sq[t] += s_sq[t + off]; }
        __syncthreads();
    }
    if (t == 0) {
        float inv = 1.f / (float)(BB * NN);
        float mean = s_sum[0] * inv;
        float var  = s_sq[0] * inv - mean * mean;
        float sc   = gamma[p] * rsqrtf(var + EPSBN);
        scale[p] = sc;
        bias[p]  = beta[p] - mean * sc;
    }
}

// ---------------- mega kernel: one block per batch, 8 waves ----------------
// waves_per_eu(2,2): LDS (160 KiB) pins occupancy at 1 block/CU = 2 waves/EU
// anyway; pinning max=2 tells the allocator its budget is 256 regs/wave
// (launch_bounds min alone left the heuristic aiming at 4 waves -> 128 cap).
// Phase E pairs receivers: one fr2 A-frag read feeds 4 MFMAs (2 recv x 2
// col-blocks) -> ~35% less LDS read traffic in the dominant loop. fr3 lives
// in LDS (F3LO) to pay for acc2's 128 AGPRs.
__global__ __launch_bounds__(512, 2) __attribute__((amdgpu_waves_per_eu(2, 2))) void meg_kernel(
    const float* __restrict__ x,
    const float* __restrict__ scl, const float* __restrict__ bia,
    const float* __restrict__ fr1_w, const float* __restrict__ fr1_b,
    const float* __restrict__ fr2_w, const float* __restrict__ fr2_b,
    const float* __restrict__ fr3_w, const float* __restrict__ fr3_b,
    const float* __restrict__ fo1_w, const float* __restrict__ fo1_b,
    const float* __restrict__ fo2_w, const float* __restrict__ fo2_b,
    const float* __restrict__ fo3_w, const float* __restrict__ fo3_b,
    const float* __restrict__ fc1_w, const float* __restrict__ fc1_b,
    const float* __restrict__ fc2_w, const float* __restrict__ fc2_b,
    const float* __restrict__ fc3_w, const float* __restrict__ fc3_b,
    float* __restrict__ out)
{
    __shared__ __align__(16) ushort L[LDSE];

    int b = blockIdx.x, t = threadIdx.x;
    int w = t >> 6, l = t & 63, lx = l & 15, lq = l >> 4;

    // ---- xnT [64][64] (cols 48..63 zero) @ XNTP
    for (int i = t; i < 4096; i += 512) {
        int n = i >> 6, k = i & 63;
        float v = (k < PP) ? x[b * PP * NN + k * NN + n] * scl[k] + bia[k] : 0.f;
        L[XNTP + sidx(n, k, 64)] = f2b(v);
    }
    // ---- fr1 receiver / sender halves into BIG
    for (int i = t; i < 16384; i += 512) {
        int ch = i >> 6, k = i & 63;
        L[BIGO + sidx(ch, k, 64)]         = f2b((k < PP) ? fr1_w[ch * 96 + k] : 0.f);
        L[BIGO + 16384 + sidx(ch, k, 64)] = f2b((k < PP) ? fr1_w[ch * 96 + PP + k] : 0.f);
    }
    // ---- fr3 [64][128] -> F3LO (region free in prologue)
    for (int i = t; i < 4096; i += 512) {
        int ch = i >> 6, k2 = (i & 63) * 2;
        float2 v = *(const float2*)(fr3_w + ch * 128 + k2);
        *(unsigned*)(L + F3LO + sidx(ch, k2, 128)) = pku(v.x, v.y);
    }
    __syncthreads();

    // ---- GEMM1+2 fused: S1R = fr1R.xn + b1, S1S = fr1S.xn  (each wave: 2 m-tiles)
    {
        f32x4 aR[2][4], aS[2][4];
#pragma unroll
        for (int j = 0; j < 2; ++j)
#pragma unroll
            for (int nt = 0; nt < 4; ++nt) { aR[j][nt] = (f32x4){0.f,0.f,0.f,0.f}; aS[j][nt] = (f32x4){0.f,0.f,0.f,0.f}; }
#pragma unroll
        for (int ks = 0; ks < 2; ++ks) {
            bf16x8 Bf[4];
#pragma unroll
            for (int nt = 0; nt < 4; ++nt) Bf[nt] = ldfrag(L + XNTP, nt * 16 + lx, ks * 32 + lq * 8, 64);
#pragma unroll
            for (int j = 0; j < 2; ++j) {
                bf16x8 AfR = ldfrag(L + BIGO,         (2 * w + j) * 16 + lx, ks * 32 + lq * 8, 64);
                bf16x8 AfS = ldfrag(L + BIGO + 16384, (2 * w + j) * 16 + lx, ks * 32 + lq * 8, 64);
#pragma unroll
                for (int nt = 0; nt < 4; ++nt) {
                    aR[j][nt] = MFMA(AfR, Bf[nt], aR[j][nt]);
                    aS[j][nt] = MFMA(AfS, Bf[nt], aS[j][nt]);
                }
            }
        }
        __syncthreads();   // BIG reads done; restage fr2 below
#pragma unroll
        for (int j = 0; j < 2; ++j) {
            int ch0 = (2 * w + j) * 16 + lq * 4;
            float4 bi = *(const float4*)(fr1_b + ch0);
            float4 zb = make_float4(0.f, 0.f, 0.f, 0.f);
#pragma unroll
            for (int nt = 0; nt < 4; ++nt) {
                stRaw(L + S1RO, nt * 16 + lx, ch0, 256, aR[j][nt], bi);
                stRaw(L + S1SO, nt * 16 + lx, ch0, 256, aS[j][nt], zb);
            }
        }
    }
    // ---- fr2 [128][256] -> BIG
    for (int i = t; i < 16384; i += 512) {
        int ch = i >> 7, k2 = (i & 127) * 2;
        float2 v = *(const float2*)(fr2_w + ch * 256 + k2);
        *(unsigned*)(L + BIGO + sidx(ch, k2, 256)) = pku(v.x, v.y);
    }
    // fr2 bias packed bf16 (16 regs), unpacked into acc2 init
    unsigned bc2p[16];
#pragma unroll
    for (int m = 0; m < 8; ++m) {
        float4 bi = *(const float4*)(fr2_b + m * 16 + lq * 4);
        bc2p[2 * m]     = pku(bi.x, bi.y);
        bc2p[2 * m + 1] = pku(bi.z, bi.w);
    }
    float b3c[4];
#pragma unroll
    for (int n3 = 0; n3 < 4; ++n3) b3c[n3] = fr3_b[n3 * 16 + lx];
    __syncthreads();

    // ================= phase E: 4 receiver-PAIRS per wave, zero barriers =================
    ushort* a2w = L + A2WO + w * 1024;     // wave-private [16][64]
#pragma unroll 1
    for (int i2 = 0; i2 < 4; ++i2) {
        int r0 = w * 8 + 2 * i2, r1 = r0 + 1;
        float part0[4] = {0.f, 0.f, 0.f, 0.f};
        float part1[4] = {0.f, 0.f, 0.f, 0.f};
#pragma unroll 1
        for (int p = 0; p < 2; ++p) {
            int eA = p * 32 + lx, eB = eA + 16;
            int sA0 = eA + (eA >= r0);
            int sB0 = eB + (eB >= r0); if (sB0 > 63) sB0 = 63;
            int sA1 = eA + (eA >= r1);
            int sB1 = eB + (eB >= r1); if (sB1 > 63) sB1 = 63;

            f32x4 acc2[2][8][2];
#pragma unroll
            for (int m = 0; m < 8; ++m) {
                f32x4 bi;
                bi[0] = loF(bc2p[2 * m]);     bi[1] = hiF(bc2p[2 * m]);
                bi[2] = loF(bc2p[2 * m + 1]); bi[3] = hiF(bc2p[2 * m + 1]);
                acc2[0][m][0] = bi; acc2[0][m][1] = bi;
                acc2[1][m][0] = bi; acc2[1][m][1] = bi;
            }
#pragma unroll
            for (int ks = 0; ks < 8; ++ks) {
                int ko = ks * 32 + lq * 8;
                U8 fr0v, fr1v, fa0, fb0, fa1, fb1;
                fr0v.v = ldfrag(L + S1RO, r0,  ko, 256);   // wave-uniform row: broadcast
                fr1v.v = ldfrag(L + S1RO, r1,  ko, 256);
                fa0.v  = ldfrag(L + S1SO, sA0, ko, 256);
                fb0.v  = ldfrag(L + S1SO, sB0, ko, 256);
                fa1.v  = ldfrag(L + S1SO, sA1, ko, 256);
                fb1.v  = ldfrag(L + S1SO, sB1, ko, 256);
                U8 bA0, bB0, bA1, bB1;
#pragma unroll
                for (int jj = 0; jj < 4; ++jj) {
                    float r0lo = loF(fr0v.u[jj]), r0hi = hiF(fr0v.u[jj]);
                    float r1lo = loF(fr1v.u[jj]), r1hi = hiF(fr1v.u[jj]);
                    bA0.u[jj] = pku(fmaxf(r0lo + loF(fa0.u[jj]), 0.f), fmaxf(r0hi + hiF(fa0.u[jj]), 0.f));
                    bB0.u[jj] = pku(fmaxf(r0lo + loF(fb0.u[jj]), 0.f), fmaxf(r0hi + hiF(fb0.u[jj]), 0.f));
                    bA1.u[jj] = pku(fmaxf(r1lo + loF(fa1.u[jj]), 0.f), fmaxf(r1hi + hiF(fa1.u[jj]), 0.f));
                    bB1.u[jj] = pku(fmaxf(r1lo + loF(fb1.u[jj]), 0.f), fmaxf(r1hi + hiF(fb1.u[jj]), 0.f));
                }
#pragma unroll
                for (int m = 0; m < 8; ++m) {
                    bf16x8 Af = ldfrag(L + BIGO, m * 16 + lx, ko, 256);   // shared by 4 MFMAs
                    acc2[0][m][0] = MFMA(Af, bA0.v, acc2[0][m][0]);
                    acc2[0][m][1] = MFMA(Af, bB0.v, acc2[0][m][1]);
                    acc2[1][m][0] = MFMA(Af, bA1.v, acc2[1][m][0]);
                    acc2[1][m][1] = MFMA(Af, bB1.v, acc2[1][m][1]);
                }
            }
            // ---- epilogue: fr3 GEMM via a2w [16][64] K-halves; bW shared across pair
#pragma unroll
            for (int cc = 0; cc < 2; ++cc) {
                f32x4 acc3[2][4];
#pragma unroll
                for (int r2 = 0; r2 < 2; ++r2)
#pragma unroll
                    for (int n3 = 0; n3 < 4; ++n3) acc3[r2][n3] = (f32x4){0.f,0.f,0.f,0.f};
#pragma unroll
                for (int h = 0; h < 2; ++h) {
                    bf16x8 bW[4][2];
#pragma unroll
                    for (int n3 = 0; n3 < 4; ++n3)
#pragma unroll
                        for (int k3 = 0; k3 < 2; ++k3)
                            bW[n3][k3] = ldfrag(L + F3LO, n3 * 16 + lx, (2 * h + k3) * 32 + lq * 8, 128);
#pragma unroll
                    for (int r2 = 0; r2 < 2; ++r2) {
#pragma unroll
                        for (int mm = 0; mm < 4; ++mm)
                            stAct0(a2w, lx, mm * 16 + lq * 4, 64, acc2[r2][4 * h + mm][cc]);
#pragma unroll
                        for (int k3 = 0; k3 < 2; ++k3) {
                            bf16x8 af = ldfrag(a2w, lx, k3 * 32 + lq * 8, 64);
#pragma unroll
                            for (int n3 = 0; n3 < 4; ++n3)
                                acc3[r2][n3] = MFMA(af, bW[n3][k3], acc3[r2][n3]);
                        }
                    }
                }
                bool mpad = (p == 1) && (cc == 1) && (lq == 3);
#pragma unroll
                for (int n3 = 0; n3 < 4; ++n3) {
                    float bv = b3c[n3];
                    float s0 = fmaxf(acc3[0][n3][0] + bv, 0.f) + fmaxf(acc3[0][n3][1] + bv, 0.f)
                             + fmaxf(acc3[0][n3][2] + bv, 0.f);
                    float s03 = fmaxf(acc3[0][n3][3] + bv, 0.f);
                    part0[n3] += s0 + (mpad ? 0.f : s03);
                    float s1 = fmaxf(acc3[1][n3][0] + bv, 0.f) + fmaxf(acc3[1][n3][1] + bv, 0.f)
                             + fmaxf(acc3[1][n3][2] + bv, 0.f);
                    float s13 = fmaxf(acc3[1][n3][3] + bv, 0.f);
                    part1[n3] += s1 + (mpad ? 0.f : s13);
                }
            }
        }
#pragma unroll
        for (int n3 = 0; n3 < 4; ++n3) {
            part0[n3] += __shfl_xor(part0[n3], 16, 64);
            part0[n3] += __shfl_xor(part0[n3], 32, 64);
            part1[n3] += __shfl_xor(part1[n3], 16, 64);
            part1[n3] += __shfl_xor(part1[n3], 32, 64);
        }
        if (lq == 0) {
#pragma unroll
            for (int n3 = 0; n3 < 4; ++n3) {
                L[S1RO + sidx(r0, n3 * 16 + lx, 256)] = f2b(part0[n3]);
                L[S1RO + sidx(r1, n3 * 16 + lx, 256)] = f2b(part1[n3]);
            }
        }
    }
    __syncthreads();

    // ================= phase N =================
    // fo1 -> BIG [256][128] (cols 0..63 ebar part, 64..111 xn part)
    for (int i = t; i < 32768; i += 512) {
        int ch = i >> 7, k = i & 127;
        float v = 0.f;
        if (k < 64)       v = fo1_w[ch * 112 + PP + k];
        else if (k < 112) v = fo1_w[ch * 112 + (k - 64)];
        L[BIGO + sidx(ch, k, 128)] = f2b(v);
    }
    // restage xnT (clobbered by waves 4..7 a2w in phase E)
    for (int i = t; i < 4096; i += 512) {
        int n = i >> 6, k = i & 63;
        float v = (k < PP) ? x[b * PP * NN + k * NN + n] * scl[k] + bia[k] : 0.f;
        L[XNTP + sidx(n, k, 64)] = f2b(v);
    }
    __syncthreads();

    // L1N: M=256 (wave: 2 m-tiles), N=64 nodes, K=128 (ks 0,1 ebar from S1RO; ks 2,3 from XNTP)
    {
        f32x4 accN[2][4];
#pragma unroll
        for (int j = 0; j < 2; ++j)
#pragma unroll
            for (int nt = 0; nt < 4; ++nt) accN[j][nt] = (f32x4){0.f,0.f,0.f,0.f};
#pragma unroll
        for (int ks = 0; ks < 4; ++ks) {
            bf16x8 Bf[4];
#pragma unroll
            for (int nt = 0; nt < 4; ++nt)
                Bf[nt] = (ks < 2) ? ldfrag(L + S1RO, nt * 16 + lx, ks * 32 + lq * 8, 256)
                                  : ldfrag(L + XNTP, nt * 16 + lx, (ks - 2) * 32 + lq * 8, 64);
#pragma unroll
            for (int j = 0; j < 2; ++j) {
                bf16x8 Af = ldfrag(L + BIGO, (2 * w + j) * 16 + lx, ks * 32 + lq * 8, 128);
#pragma unroll
                for (int nt = 0; nt < 4; ++nt) accN[j][nt] = MFMA(Af, Bf[nt], accN[j][nt]);
            }
        }
        __syncthreads();   // BIG/S1RO/XNTP reads done
#pragma unroll
        for (int j = 0; j < 2; ++j) {
            int ch0 = (2 * w + j) * 16 + lq * 4;
            float4 bi = *(const float4*)(fo1_b + ch0);
#pragma unroll
            for (int nt = 0; nt < 4; ++nt)
                stAct(L + S1SO, nt * 16 + lx, ch0, 256, accN[j][nt], bi);
        }
    }
    // fo2 -> BIG [128][256]; fo3 -> S1RO [64][128]
    for (int i = t; i < 16384; i += 512) {
        int ch = i >> 7, k2 = (i & 127) * 2;
        float2 v = *(const float2*)(fo2_w + ch * 256 + k2);
        *(unsigned*)(L + BIGO + sidx(ch, k2, 256)) = pku(v.x, v.y);
    }
    for (int i = t; i < 4096; i += 512) {
        int ch = i >> 6, k2 = (i & 63) * 2;
        float2 v = *(const float2*)(fo3_w + ch * 128 + k2);
        *(unsigned*)(L + S1RO + sidx(ch, k2, 128)) = pku(v.x, v.y);
    }
    __syncthreads();

    // L2N: M=128 (wave: m-tile w), N=64, K=256 -> act2N @ F3LO [64][128]
    {
        f32x4 a2N[4];
#pragma unroll
        for (int nt = 0; nt < 4; ++nt) a2N[nt] = (f32x4){0.f,0.f,0.f,0.f};
#pragma unroll
        for (int ks = 0; ks < 8; ++ks) {
            bf16x8 Bf[4];
#pragma unroll
            for (int nt = 0; nt < 4; ++nt) Bf[nt] = ldfrag(L + S1SO, nt * 16 + lx, ks * 32 + lq * 8, 256);
            bf16x8 Af = ldfrag(L + BIGO, w * 16 + lx, ks * 32 + lq * 8, 256);
#pragma unroll
            for (int nt = 0; nt < 4; ++nt) a2N[nt] = MFMA(Af, Bf[nt], a2N[nt]);
        }
        int ch0 = w * 16 + lq * 4;
        float4 bi = *(const float4*)(fo2_b + ch0);
#pragma unroll
        for (int nt = 0; nt < 4; ++nt)
            stAct(L + F3LO, nt * 16 + lx, ch0, 128, a2N[nt], bi);
    }
    __syncthreads();

    // L3N: M=64 (fo3 ch), N=64 nodes, K=128 (waves 0..3); relu+bias, sum over nodes
    if (w < 4) {
        f32x4 a3N[4];
#pragma unroll
        for (int nt = 0; nt < 4; ++nt) a3N[nt] = (f32x4){0.f,0.f,0.f,0.f};
#pragma unroll
        for (int ks3 = 0; ks3 < 4; ++ks3) {
            bf16x8 Af = ldfrag(L + S1RO, 16 * w + lx, ks3 * 32 + lq * 8, 128);
#pragma unroll
            for (int nt = 0; nt < 4; ++nt) {
                bf16x8 Bf = ldfrag(L + F3LO, nt * 16 + lx, ks3 * 32 + lq * 8, 128);
                a3N[nt] = MFMA(Af, Bf, a3N[nt]);
            }
        }
        float4 b3 = *(const float4*)(fo3_b + 16 * w + lq * 4);
        float o0 = 0.f, o1 = 0.f, o2 = 0.f, o3 = 0.f;
#pragma unroll
        for (int nt = 0; nt < 4; ++nt) {
            o0 += fmaxf(a3N[nt][0] + b3.x, 0.f);
            o1 += fmaxf(a3N[nt][1] + b3.y, 0.f);
            o2 += fmaxf(a3N[nt][2] + b3.z, 0.f);
            o3 += fmaxf(a3N[nt][3] + b3.w, 0.f);
        }
#pragma unroll
        for (int off = 8; off >= 1; off >>= 1) {
            o0 += __shfl_xor(o0, off, 16);
            o1 += __shfl_xor(o1, off, 16);
            o2 += __shfl_xor(o2, off, 16);
            o3 += __shfl_xor(o3, off, 16);
        }
        if (lx == 0) {
            float* red = (float*)(L + REDO);
            *(float4*)&red[16 * w + lq * 4] = make_float4(o0, o1, o2, o3);
        }
    }
    __syncthreads();

    // ---- final FCs (fp32)
    {
        float* red = (float*)(L + REDO);
        float* h1  = red + 64;
        float* h2  = red + 96;
        if (t < 25) {
            float s = fc1_b[t];
            for (int k = 0; k < 64; ++k) s += fc1_w[t * 64 + k] * red[k];
            h1[t] = s;
        }
        __syncthreads();
        if (t < 15) {
            float s = fc2_b[t];
            for (int k = 0; k < 25; ++k) s += fc2_w[t * 25 + k] * h1[k];
            h2[t] = s;
        }
        __syncthreads();
        if (t < 5) {
            float s = fc3_b[t];
            for (int k = 0; k < 15; ++k) s += fc3_w[t * 15 + k] * h2[k];
            out[b * 5 + t] = s;
        }
    }
}

extern "C" void kernel_launch(void* const* d_in, const int* in_sizes, int n_in,
                              void* d_out, int out_size, void* d_ws, size_t ws_size,
                              hipStream_t stream)
{
    const float* x        = (const float*)d_in[0];
    const float* bn_gamma = (const float*)d_in[3];
    const float* bn_beta  = (const float*)d_in[4];
    const float* fr1_w = (const float*)d_in[5];
    const float* fr1_b = (const float*)d_in[6];
    const float* fr2_w = (const float*)d_in[7];
    const float* fr2_b = (const float*)d_in[8];
    const float* fr3_w = (const float*)d_in[9];
    const float* fr3_b = (const float*)d_in[10];
    const float* fo1_w = (const float*)d_in[11];
    const float* fo1_b = (const float*)d_in[12];
    const float* fo2_w = (const float*)d_in[13];
    const float* fo2_b = (const float*)d_in[14];
    const float* fo3_w = (const float*)d_in[15];
    const float* fo3_b = (const float*)d_in[16];
    const float* fc1_w = (const float*)d_in[17];
    const float* fc1_b = (const float*)d_in[18];
    const float* fc2_w = (const float*)d_in[19];
    const float* fc2_b = (const float*)d_in[20];
    const float* fc3_w = (const float*)d_in[21];
    const float* fc3_b = (const float*)d_in[22];

    float* ws    = (float*)d_ws;
    float* scale = ws;
    float* bias  = ws + 64;
    float* out   = (float*)d_out;

    bn_stats_kernel<<<dim3(PP), dim3(256), 0, stream>>>(x, bn_gamma, bn_beta, scale, bias);
    meg_kernel<<<dim3(BB), dim3(512), 0, stream>>>(
        x, scale, bias,
        fr1_w, fr1_b, fr2_w, fr2_b, fr3_w, fr3_b,
        fo1_w, fo1_b, fo2_w, fo2_b, fo3_w, fo3_b,
        fc1_w, fc1_b, fc2_w, fc2_b, fc3_w, fc3_b, out);
}

// Round 6
// 277.658 us; speedup vs baseline: 1.0731x; 1.0731x over previous
//
#include <hip/hip_runtime.h>
#include <hip/hip_bf16.h>

#define BB 256
#define PP 48
#define NN 64
#define EPSBN 1e-5f

typedef __attribute__((ext_vector_type(8))) short bf16x8;
typedef __attribute__((ext_vector_type(4))) float f32x4;

// ---- LDS regions (ushort offsets), total 81920 ushorts = 163840 B (160 KiB) ----
// 12-wave (768-thread) layout:
#define BIGO 0       // 32768: fr1R/[+16384]fr1S -> fr2 [128][256]   | N: fo1 [256][128] -> fo2 [128][256]
#define S1SO 32768   // 16384: S1S [64][256]                          | N: act1N [64][256]
#define S1RO 49152   // 16384: S1R [64][256]; cols 0..63 ebar; N: +xn cols 64..127 -> fo3 [64][128]
#define F3LO 65536   //  8192: fr3 [64][128] (phase E B-operand)      | N: act2N [64][128]
#define A2WO 73728   //  6144: phase E: 12 waves x 512 ([16][32] quarters)
#define XNTP 73728   //  4096: prologue xnT [64][64] (aliases A2WO; dead before phase E)
#define REDO 79872   //  2048: red/h1/h2 floats
#define LDSE 81920

union U8 { bf16x8 v; unsigned u[4]; };

__device__ __forceinline__ unsigned pku(float a, float b) {
    union { __hip_bfloat162 h; unsigned u; } cv;
    cv.h = __float22bfloat162_rn(make_float2(a, b));
    return cv.u;
}
__device__ __forceinline__ ushort f2b(float f) {
    union { float f; unsigned u; } a; a.f = f;
    unsigned u = a.u + 0x7FFFu + ((a.u >> 16) & 1u);
    return (ushort)(u >> 16);
}
__device__ __forceinline__ float loF(unsigned u) { union { unsigned x; float f; } c; c.x = u << 16; return c.f; }
__device__ __forceinline__ float hiF(unsigned u) { union { unsigned x; float f; } c; c.x = u & 0xffff0000u; return c.f; }

__device__ __forceinline__ int sidx(int row, int k, int kpad) {
    return row * kpad + ((((k >> 3) ^ (row & 7)) << 3) | (k & 7));
}
__device__ __forceinline__ bf16x8 ldfrag(const ushort* buf, int row, int k, int kpad) {
    return *(const bf16x8*)(buf + row * kpad + (((k >> 3) ^ (row & 7)) << 3));
}
// 32-col wave-private buffer: 2-bit XOR swizzle
__device__ __forceinline__ bf16x8 ldfrag32(const ushort* buf, int row, int k) {
    return *(const bf16x8*)(buf + row * 32 + ((((k >> 3) ^ (row & 3))) << 3));
}
__device__ __forceinline__ f32x4 MFMA(bf16x8 a, bf16x8 b, f32x4 c) {
    return __builtin_amdgcn_mfma_f32_16x16x32_bf16(a, b, c, 0, 0, 0);
}
__device__ __forceinline__ void stAct(ushort* buf, int row, int c0, int kpad, f32x4 a, float4 bi) {
    uint2 o;
    o.x = pku(fmaxf(a[0] + bi.x, 0.f), fmaxf(a[1] + bi.y, 0.f));
    o.y = pku(fmaxf(a[2] + bi.z, 0.f), fmaxf(a[3] + bi.w, 0.f));
    *(uint2*)(buf + row * kpad + ((((c0 >> 3) ^ (row & 7)) << 3) | (c0 & 7))) = o;
}
// bias folded into accumulator init: store relu(acc); 32-col swizzle variant
__device__ __forceinline__ void stAct032(ushort* buf, int row, int c0, f32x4 a) {
    uint2 o;
    o.x = pku(fmaxf(a[0], 0.f), fmaxf(a[1], 0.f));
    o.y = pku(fmaxf(a[2], 0.f), fmaxf(a[3], 0.f));
    *(uint2*)(buf + row * 32 + ((((c0 >> 3) ^ (row & 3)) << 3) | (c0 & 7))) = o;
}
__device__ __forceinline__ void stRaw(ushort* buf, int row, int c0, int kpad, f32x4 a, float4 bi) {
    uint2 o;
    o.x = pku(a[0] + bi.x, a[1] + bi.y);
    o.y = pku(a[2] + bi.z, a[3] + bi.w);
    *(uint2*)(buf + row * kpad + ((((c0 >> 3) ^ (row & 7)) << 3) | (c0 & 7))) = o;
}

// ---------------- batchnorm stats ----------------
__global__ __launch_bounds__(256) void bn_stats_kernel(
    const float* __restrict__ x, const float* __restrict__ gamma,
    const float* __restrict__ beta, float* __restrict__ scale, float* __restrict__ bias)
{
    __shared__ float s_sum[256], s_sq[256];
    int p = blockIdx.x, t = threadIdx.x;
    float sum = 0.f, sq = 0.f;
    for (int i = t; i < BB * NN; i += 256) {
        int b = i >> 6, n = i & 63;
        float v = x[b * PP * NN + p * NN + n];
        sum += v; sq += v * v;
    }
    s_sum[t] = sum; s_sq[t] = sq;
    __syncthreads();
    for (int off = 128; off > 0; off >>= 1) {
        if (t < off) { s_sum[t] += s_sum[t + off]; s_sq[t] += s_sq[t + off]; }
        __syncthreads();
    }
    if (t == 0) {
        float inv = 1.f / (float)(BB * NN);
        float mean = s_sum[0] * inv;
        float var  = s_sq[0] * inv - mean * mean;
        float sc   = gamma[p] * rsqrtf(var + EPSBN);
        scale[p] = sc;
        bias[p]  = beta[p] - mean * sc;
    }
}

// ---------------- mega kernel: one block per batch, 12 waves (3/SIMD) ----------------
// 768 threads raise occupancy 2->3 waves/SIMD (the profile showed both pipes
// idle at 2 waves: latency-bound). Register budget/wave = 512/3 = 170 total
// (unified VGPR+AGPR): fr3 lives in LDS (F3LO), acc2 stays [8][2]=64 AGPR,
// epilogue goes through a [16][32] wave-private quarter buffer (0.5 KB/wave).
// Phase N packs xn into S1RO cols 64..127 (ebar uses 0..63) to free LDS.
__global__ __launch_bounds__(768, 3) void meg_kernel(
    const float* __restrict__ x,
    const float* __restrict__ scl, const float* __restrict__ bia,
    const float* __restrict__ fr1_w, const float* __restrict__ fr1_b,
    const float* __restrict__ fr2_w, const float* __restrict__ fr2_b,
    const float* __restrict__ fr3_w, const float* __restrict__ fr3_b,
    const float* __restrict__ fo1_w, const float* __restrict__ fo1_b,
    const float* __restrict__ fo2_w, const float* __restrict__ fo2_b,
    const float* __restrict__ fo3_w, const float* __restrict__ fo3_b,
    const float* __restrict__ fc1_w, const float* __restrict__ fc1_b,
    const float* __restrict__ fc2_w, const float* __restrict__ fc2_b,
    const float* __restrict__ fc3_w, const float* __restrict__ fc3_b,
    float* __restrict__ out)
{
    __shared__ __align__(16) ushort L[LDSE];

    int b = blockIdx.x, t = threadIdx.x;
    int w = t >> 6, l = t & 63, lx = l & 15, lq = l >> 4;

    // ---- xnT [64][64] (cols 48..63 zero) @ XNTP (prologue only)
    for (int i = t; i < 4096; i += 768) {
        int n = i >> 6, k = i & 63;
        float v = (k < PP) ? x[b * PP * NN + k * NN + n] * scl[k] + bia[k] : 0.f;
        L[XNTP + sidx(n, k, 64)] = f2b(v);
    }
    // ---- fr1 receiver / sender halves into BIG
    for (int i = t; i < 16384; i += 768) {
        int ch = i >> 6, k = i & 63;
        L[BIGO + sidx(ch, k, 64)]         = f2b((k < PP) ? fr1_w[ch * 96 + k] : 0.f);
        L[BIGO + 16384 + sidx(ch, k, 64)] = f2b((k < PP) ? fr1_w[ch * 96 + PP + k] : 0.f);
    }
    // ---- fr3 [64][128] -> F3LO
    for (int i = t; i < 4096; i += 768) {
        int ch = i >> 6, k2 = (i & 63) * 2;
        float2 v = *(const float2*)(fr3_w + ch * 128 + k2);
        *(unsigned*)(L + F3LO + sidx(ch, k2, 128)) = pku(v.x, v.y);
    }
    __syncthreads();

    // ---- GEMM1+2 fused: S1R = fr1R.xn + b1, S1S = fr1S.xn (16 m-tiles over 12 waves)
    for (int mt = w; mt < 16; mt += 12) {
        f32x4 aR[4], aS[4];
#pragma unroll
        for (int nt = 0; nt < 4; ++nt) { aR[nt] = (f32x4){0.f,0.f,0.f,0.f}; aS[nt] = (f32x4){0.f,0.f,0.f,0.f}; }
#pragma unroll
        for (int ks = 0; ks < 2; ++ks) {
            bf16x8 AfR = ldfrag(L + BIGO,         mt * 16 + lx, ks * 32 + lq * 8, 64);
            bf16x8 AfS = ldfrag(L + BIGO + 16384, mt * 16 + lx, ks * 32 + lq * 8, 64);
#pragma unroll
            for (int nt = 0; nt < 4; ++nt) {
                bf16x8 Bf = ldfrag(L + XNTP, nt * 16 + lx, ks * 32 + lq * 8, 64);
                aR[nt] = MFMA(AfR, Bf, aR[nt]);
                aS[nt] = MFMA(AfS, Bf, aS[nt]);
            }
        }
        int ch0 = mt * 16 + lq * 4;
        float4 bi = *(const float4*)(fr1_b + ch0);
        float4 zb = make_float4(0.f, 0.f, 0.f, 0.f);
#pragma unroll
        for (int nt = 0; nt < 4; ++nt) {
            stRaw(L + S1RO, nt * 16 + lx, ch0, 256, aR[nt], bi);
            stRaw(L + S1SO, nt * 16 + lx, ch0, 256, aS[nt], zb);
        }
    }
    __syncthreads();   // BIG/XNTP reads done; restage fr2 below

    // ---- fr2 [128][256] -> BIG
    for (int i = t; i < 16384; i += 768) {
        int ch = i >> 7, k2 = (i & 127) * 2;
        float2 v = *(const float2*)(fr2_w + ch * 256 + k2);
        *(unsigned*)(L + BIGO + sidx(ch, k2, 256)) = pku(v.x, v.y);
    }
    // fr2 bias packed bf16 (16 regs); fr3 bias (4 regs)
    unsigned bc2p[16];
#pragma unroll
    for (int m = 0; m < 8; ++m) {
        float4 bi = *(const float4*)(fr2_b + m * 16 + lq * 4);
        bc2p[2 * m]     = pku(bi.x, bi.y);
        bc2p[2 * m + 1] = pku(bi.z, bi.w);
    }
    float b3c[4];
#pragma unroll
    for (int n3 = 0; n3 < 4; ++n3) b3c[n3] = fr3_b[n3 * 16 + lx];
    __syncthreads();

    // ================= phase E: receivers strided over 12 waves, zero barriers =================
    ushort* a2w = L + A2WO + w * 512;     // wave-private [16][32]
#pragma unroll 1
    for (int r = w; r < 64; r += 12) {
        float part[4] = {0.f, 0.f, 0.f, 0.f};
#pragma unroll 1
        for (int p = 0; p < 2; ++p) {
            int eA = p * 32 + lx, eB = eA + 16;
            int sA = eA + (eA >= r);
            int sB = eB + (eB >= r); if (sB > 63) sB = 63;   // pad edge 63

            f32x4 acc2[8][2];
#pragma unroll
            for (int m = 0; m < 8; ++m) {
                f32x4 bi;
                bi[0] = loF(bc2p[2 * m]);     bi[1] = hiF(bc2p[2 * m]);
                bi[2] = loF(bc2p[2 * m + 1]); bi[3] = hiF(bc2p[2 * m + 1]);
                acc2[m][0] = bi; acc2[m][1] = bi;
            }
#pragma unroll
            for (int ks = 0; ks < 8; ++ks) {
                int ko = ks * 32 + lq * 8;
                U8 fr, fa, fb;
                fr.v = ldfrag(L + S1RO, r,  ko, 256);   // wave-uniform row: broadcast
                fa.v = ldfrag(L + S1SO, sA, ko, 256);
                fb.v = ldfrag(L + S1SO, sB, ko, 256);
                U8 bA, bB;
#pragma unroll
                for (int jj = 0; jj < 4; ++jj) {
                    float r0 = loF(fr.u[jj]), r1 = hiF(fr.u[jj]);
                    bA.u[jj] = pku(fmaxf(r0 + loF(fa.u[jj]), 0.f), fmaxf(r1 + hiF(fa.u[jj]), 0.f));
                    bB.u[jj] = pku(fmaxf(r0 + loF(fb.u[jj]), 0.f), fmaxf(r1 + hiF(fb.u[jj]), 0.f));
                }
#pragma unroll
                for (int m = 0; m < 8; ++m) {
                    bf16x8 Af = ldfrag(L + BIGO, m * 16 + lx, ko, 256);
                    acc2[m][0] = MFMA(Af, bA.v, acc2[m][0]);
                    acc2[m][1] = MFMA(Af, bB.v, acc2[m][1]);
                }
            }
            // ---- epilogue: fr3 GEMM through [16][32] quarters, fr3 from LDS
#pragma unroll
            for (int cc = 0; cc < 2; ++cc) {
                f32x4 acc3[4];
#pragma unroll
                for (int n3 = 0; n3 < 4; ++n3) acc3[n3] = (f32x4){0.f,0.f,0.f,0.f};
#pragma unroll
                for (int h = 0; h < 4; ++h) {
                    stAct032(a2w, lx, lq * 4,      acc2[2 * h][cc]);
                    stAct032(a2w, lx, 16 + lq * 4, acc2[2 * h + 1][cc]);
                    bf16x8 af = ldfrag32(a2w, lx, lq * 8);
#pragma unroll
                    for (int n3 = 0; n3 < 4; ++n3) {
                        bf16x8 bW = ldfrag(L + F3LO, n3 * 16 + lx, h * 32 + lq * 8, 128);
                        acc3[n3] = MFMA(af, bW, acc3[n3]);
                    }
                }
                bool mpad = (p == 1) && (cc == 1) && (lq == 3);
#pragma unroll
                for (int n3 = 0; n3 < 4; ++n3) {
                    float bv = b3c[n3];
                    float s = fmaxf(acc3[n3][0] + bv, 0.f) + fmaxf(acc3[n3][1] + bv, 0.f)
                            + fmaxf(acc3[n3][2] + bv, 0.f);
                    float s3 = fmaxf(acc3[n3][3] + bv, 0.f);
                    part[n3] += s + (mpad ? 0.f : s3);
                }
            }
        }
#pragma unroll
        for (int n3 = 0; n3 < 4; ++n3) {
            part[n3] += __shfl_xor(part[n3], 16, 64);
            part[n3] += __shfl_xor(part[n3], 32, 64);
        }
        if (lq == 0) {
#pragma unroll
            for (int n3 = 0; n3 < 4; ++n3)
                L[S1RO + sidx(r, n3 * 16 + lx, 256)] = f2b(part[n3]);
        }
    }
    __syncthreads();

    // ================= phase N =================
    // fo1 -> BIG [256][128] (cols 0..63 ebar part, 64..111 xn part)
    for (int i = t; i < 32768; i += 768) {
        int ch = i >> 7, k = i & 127;
        float v = 0.f;
        if (k < 64)       v = fo1_w[ch * 112 + PP + k];
        else if (k < 112) v = fo1_w[ch * 112 + (k - 64)];
        L[BIGO + sidx(ch, k, 128)] = f2b(v);
    }
    // xn -> S1RO cols 64..127 (48 real + 16 zero); ebar already in cols 0..63
    for (int i = t; i < 4096; i += 768) {
        int n = i >> 6, k = i & 63;
        float v = (k < PP) ? x[b * PP * NN + k * NN + n] * scl[k] + bia[k] : 0.f;
        L[S1RO + sidx(n, 64 + k, 256)] = f2b(v);
    }
    __syncthreads();

    // L1N: M=256 (16 m-tiles over 12 waves), N=64 nodes, K=128 (all from S1RO)
    for (int mt = w; mt < 16; mt += 12) {
        f32x4 accN[4];
#pragma unroll
        for (int nt = 0; nt < 4; ++nt) accN[nt] = (f32x4){0.f,0.f,0.f,0.f};
#pragma unroll
        for (int ks = 0; ks < 4; ++ks) {
            bf16x8 Af = ldfrag(L + BIGO, mt * 16 + lx, ks * 32 + lq * 8, 128);
#pragma unroll
            for (int nt = 0; nt < 4; ++nt) {
                bf16x8 Bf = ldfrag(L + S1RO, nt * 16 + lx, ks * 32 + lq * 8, 256);
                accN[nt] = MFMA(Af, Bf, accN[nt]);
            }
        }
        int ch0 = mt * 16 + lq * 4;
        float4 bi = *(const float4*)(fo1_b + ch0);
#pragma unroll
        for (int nt = 0; nt < 4; ++nt)
            stAct(L + S1SO, nt * 16 + lx, ch0, 256, accN[nt], bi);
    }
    __syncthreads();   // BIG/S1RO reads done

    // fo2 -> BIG [128][256]; fo3 -> S1RO [64][128]
    for (int i = t; i < 16384; i += 768) {
        int ch = i >> 7, k2 = (i & 127) * 2;
        float2 v = *(const float2*)(fo2_w + ch * 256 + k2);
        *(unsigned*)(L + BIGO + sidx(ch, k2, 256)) = pku(v.x, v.y);
    }
    for (int i = t; i < 4096; i += 768) {
        int ch = i >> 6, k2 = (i & 63) * 2;
        float2 v = *(const float2*)(fo3_w + ch * 128 + k2);
        *(unsigned*)(L + S1RO + sidx(ch, k2, 128)) = pku(v.x, v.y);
    }
    __syncthreads();

    // L2N: M=128 (waves 0..7), N=64, K=256 -> act2N @ F3LO [64][128]
    if (w < 8) {
        f32x4 a2N[4];
#pragma unroll
        for (int nt = 0; nt < 4; ++nt) a2N[nt] = (f32x4){0.f,0.f,0.f,0.f};
#pragma unroll
        for (int ks = 0; ks < 8; ++ks) {
            bf16x8 Af = ldfrag(L + BIGO, w * 16 + lx, ks * 32 + lq * 8, 256);
#pragma unroll
            for (int nt = 0; nt < 4; ++nt) {
                bf16x8 Bf = ldfrag(L + S1SO, nt * 16 + lx, ks * 32 + lq * 8, 256);
                a2N[nt] = MFMA(Af, Bf, a2N[nt]);
            }
        }
        int ch0 = w * 16 + lq * 4;
        float4 bi = *(const float4*)(fo2_b + ch0);
#pragma unroll
        for (int nt = 0; nt < 4; ++nt)
            stAct(L + F3LO, nt * 16 + lx, ch0, 128, a2N[nt], bi);
    }
    __syncthreads();

    // L3N: M=64 (fo3 ch), N=64 nodes, K=128 (waves 0..3); relu+bias, sum over nodes
    if (w < 4) {
        f32x4 a3N[4];
#pragma unroll
        for (int nt = 0; nt < 4; ++nt) a3N[nt] = (f32x4){0.f,0.f,0.f,0.f};
#pragma unroll
        for (int ks3 = 0; ks3 < 4; ++ks3) {
            bf16x8 Af = ldfrag(L + S1RO, 16 * w + lx, ks3 * 32 + lq * 8, 128);
#pragma unroll
            for (int nt = 0; nt < 4; ++nt) {
                bf16x8 Bf = ldfrag(L + F3LO, nt * 16 + lx, ks3 * 32 + lq * 8, 128);
                a3N[nt] = MFMA(Af, Bf, a3N[nt]);
            }
        }
        float4 b3 = *(const float4*)(fo3_b + 16 * w + lq * 4);
        float o0 = 0.f, o1 = 0.f, o2 = 0.f, o3 = 0.f;
#pragma unroll
        for (int nt = 0; nt < 4; ++nt) {
            o0 += fmaxf(a3N[nt][0] + b3.x, 0.f);
            o1 += fmaxf(a3N[nt][1] + b3.y, 0.f);
            o2 += fmaxf(a3N[nt][2] + b3.z, 0.f);
            o3 += fmaxf(a3N[nt][3] + b3.w, 0.f);
        }
#pragma unroll
        for (int off = 8; off >= 1; off >>= 1) {
            o0 += __shfl_xor(o0, off, 16);
            o1 += __shfl_xor(o1, off, 16);
            o2 += __shfl_xor(o2, off, 16);
            o3 += __shfl_xor(o3, off, 16);
        }
        if (lx == 0) {
            float* red = (float*)(L + REDO);
            *(float4*)&red[16 * w + lq * 4] = make_float4(o0, o1, o2, o3);
        }
    }
    __syncthreads();

    // ---- final FCs (fp32)
    {
        float* red = (float*)(L + REDO);
        float* h1  = red + 64;
        float* h2  = red + 96;
        if (t < 25) {
            float s = fc1_b[t];
            for (int k = 0; k < 64; ++k) s += fc1_w[t * 64 + k] * red[k];
            h1[t] = s;
        }
        __syncthreads();
        if (t < 15) {
            float s = fc2_b[t];
            for (int k = 0; k < 25; ++k) s += fc2_w[t * 25 + k] * h1[k];
            h2[t] = s;
        }
        __syncthreads();
        if (t < 5) {
            float s = fc3_b[t];
            for (int k = 0; k < 15; ++k) s += fc3_w[t * 15 + k] * h2[k];
            out[b * 5 + t] = s;
        }
    }
}

extern "C" void kernel_launch(void* const* d_in, const int* in_sizes, int n_in,
                              void* d_out, int out_size, void* d_ws, size_t ws_size,
                              hipStream_t stream)
{
    const float* x        = (const float*)d_in[0];
    const float* bn_gamma = (const float*)d_in[3];
    const float* bn_beta  = (const float*)d_in[4];
    const float* fr1_w = (const float*)d_in[5];
    const float* fr1_b = (const float*)d_in[6];
    const float* fr2_w = (const float*)d_in[7];
    const float* fr2_b = (const float*)d_in[8];
    const float* fr3_w = (const float*)d_in[9];
    const float* fr3_b = (const float*)d_in[10];
    const float* fo1_w = (const float*)d_in[11];
    const float* fo1_b = (const float*)d_in[12];
    const float* fo2_w = (const float*)d_in[13];
    const float* fo2_b = (const float*)d_in[14];
    const float* fo3_w = (const float*)d_in[15];
    const float* fo3_b = (const float*)d_in[16];
    const float* fc1_w = (const float*)d_in[17];
    const float* fc1_b = (const float*)d_in[18];
    const float* fc2_w = (const float*)d_in[19];
    const float* fc2_b = (const float*)d_in[20];
    const float* fc3_w = (const float*)d_in[21];
    const float* fc3_b = (const float*)d_in[22];

    float* ws    = (float*)d_ws;
    float* scale = ws;
    float* bias  = ws + 64;
    float* out   = (float*)d_out;

    bn_stats_kernel<<<dim3(PP), dim3(256), 0, stream>>>(x, bn_gamma, bn_beta, scale, bias);
    meg_kernel<<<dim3(BB), dim3(768), 0, stream>>>(
        x, scale, bias,
        fr1_w, fr1_b, fr2_w, fr2_b, fr3_w, fr3_b,
        fo1_w, fo1_b, fo2_w, fo2_b, fo3_w, fo3_b,
        fc1_w, fc1_b, fc2_w, fc2_b, fc3_w, fc3_b, out);
}

// Round 7
// 272.578 us; speedup vs baseline: 1.0931x; 1.0186x over previous
//
#include <hip/hip_runtime.h>
#include <hip/hip_bf16.h>

#define BB 256
#define PP 48
#define NN 64
#define EPSBN 1e-5f

typedef __attribute__((ext_vector_type(8))) short bf16x8;
typedef __attribute__((ext_vector_type(4))) float f32x4;

// ---- LDS regions (ushort offsets), total 81920 ushorts = 163840 B (160 KiB) ----
// 12-wave (768-thread) layout:
#define BIGO 0       // 32768: fr1R/[+16384]fr1S -> fr2 [128][256]   | N: fo1 [256][128] -> fo2 [128][256]
#define S1SO 32768   // 16384: S1S [64][256]                          | N: act1N [64][256]
#define S1RO 49152   // 16384: S1R [64][256]; cols 0..63 ebar; N: +xn cols 64..127 -> fo3 [64][128]
#define F3LO 65536   //  8192: fr3 [64][128] (phase E B-operand)      | N: act2N [64][128]
#define A2WO 73728   //  6144: phase E: 12 waves x 512 ([16][32] quarters)
#define XNTP 73728   //  4096: prologue xnT [64][64] (aliases A2WO; dead before phase E)
#define REDO 79872   //  2048: phase E: fr2_b[128]f32 @REDO (bias table) | N-end: red/h1/h2 floats
#define B2LO 79872   //   256 ushorts = fr2_b as 128 floats (phase E only; red overwrites later)
#define LDSE 81920

union U8 { bf16x8 v; unsigned u[4]; };

__device__ __forceinline__ unsigned pku(float a, float b) {
    union { __hip_bfloat162 h; unsigned u; } cv;
    cv.h = __float22bfloat162_rn(make_float2(a, b));
    return cv.u;
}
__device__ __forceinline__ ushort f2b(float f) {
    union { float f; unsigned u; } a; a.f = f;
    unsigned u = a.u + 0x7FFFu + ((a.u >> 16) & 1u);
    return (ushort)(u >> 16);
}
__device__ __forceinline__ float loF(unsigned u) { union { unsigned x; float f; } c; c.x = u << 16; return c.f; }
__device__ __forceinline__ float hiF(unsigned u) { union { unsigned x; float f; } c; c.x = u & 0xffff0000u; return c.f; }

__device__ __forceinline__ int sidx(int row, int k, int kpad) {
    return row * kpad + ((((k >> 3) ^ (row & 7)) << 3) | (k & 7));
}
__device__ __forceinline__ bf16x8 ldfrag(const ushort* buf, int row, int k, int kpad) {
    return *(const bf16x8*)(buf + row * kpad + (((k >> 3) ^ (row & 7)) << 3));
}
// 32-col wave-private buffer: 2-bit XOR swizzle
__device__ __forceinline__ bf16x8 ldfrag32(const ushort* buf, int row, int k) {
    return *(const bf16x8*)(buf + row * 32 + ((((k >> 3) ^ (row & 3))) << 3));
}
__device__ __forceinline__ f32x4 MFMA(bf16x8 a, bf16x8 b, f32x4 c) {
    return __builtin_amdgcn_mfma_f32_16x16x32_bf16(a, b, c, 0, 0, 0);
}
__device__ __forceinline__ void stAct(ushort* buf, int row, int c0, int kpad, f32x4 a, float4 bi) {
    uint2 o;
    o.x = pku(fmaxf(a[0] + bi.x, 0.f), fmaxf(a[1] + bi.y, 0.f));
    o.y = pku(fmaxf(a[2] + bi.z, 0.f), fmaxf(a[3] + bi.w, 0.f));
    *(uint2*)(buf + row * kpad + ((((c0 >> 3) ^ (row & 7)) << 3) | (c0 & 7))) = o;
}
// bias folded into accumulator init: store relu(acc); 32-col swizzle variant
__device__ __forceinline__ void stAct032(ushort* buf, int row, int c0, f32x4 a) {
    uint2 o;
    o.x = pku(fmaxf(a[0], 0.f), fmaxf(a[1], 0.f));
    o.y = pku(fmaxf(a[2], 0.f), fmaxf(a[3], 0.f));
    *(uint2*)(buf + row * 32 + ((((c0 >> 3) ^ (row & 3)) << 3) | (c0 & 7))) = o;
}
__device__ __forceinline__ void stRaw(ushort* buf, int row, int c0, int kpad, f32x4 a, float4 bi) {
    uint2 o;
    o.x = pku(a[0] + bi.x, a[1] + bi.y);
    o.y = pku(a[2] + bi.z, a[3] + bi.w);
    *(uint2*)(buf + row * kpad + ((((c0 >> 3) ^ (row & 7)) << 3) | (c0 & 7))) = o;
}

// ---------------- batchnorm stats ----------------
__global__ __launch_bounds__(256) void bn_stats_kernel(
    const float* __restrict__ x, const float* __restrict__ gamma,
    const float* __restrict__ beta, float* __restrict__ scale, float* __restrict__ bias)
{
    __shared__ float s_sum[256], s_sq[256];
    int p = blockIdx.x, t = threadIdx.x;
    float sum = 0.f, sq = 0.f;
    for (int i = t; i < BB * NN; i += 256) {
        int b = i >> 6, n = i & 63;
        float v = x[b * PP * NN + p * NN + n];
        sum += v; sq += v * v;
    }
    s_sum[t] = sum; s_sq[t] = sq;
    __syncthreads();
    for (int off = 128; off > 0; off >>= 1) {
        if (t < off) { s_sum[t] += s_sum[t + off]; s_sq[t] += s_sq[t + off]; }
        __syncthreads();
    }
    if (t == 0) {
        float inv = 1.f / (float)(BB * NN);
        float mean = s_sum[0] * inv;
        float var  = s_sq[0] * inv - mean * mean;
        float sc   = gamma[p] * rsqrtf(var + EPSBN);
        scale[p] = sc;
        bias[p]  = beta[p] - mean * sc;
    }
}

// ---------------- mega kernel: one block per batch, 12 waves (3/SIMD) ----------------
// R5 proved 3 waves/SIMD helps (196->182) but re-introduced ~10-dword/iter
// spills (WRITE_SIZE 107 MB): live set grazed the 170-reg budget. R6 moves
// the 16-reg fr2-bias array into an LDS table (B2LO) read per-m at acc2 init
// (broadcast ds_read_b128) - the only change vs R5.
__global__ __launch_bounds__(768, 3) void meg_kernel(
    const float* __restrict__ x,
    const float* __restrict__ scl, const float* __restrict__ bia,
    const float* __restrict__ fr1_w, const float* __restrict__ fr1_b,
    const float* __restrict__ fr2_w, const float* __restrict__ fr2_b,
    const float* __restrict__ fr3_w, const float* __restrict__ fr3_b,
    const float* __restrict__ fo1_w, const float* __restrict__ fo1_b,
    const float* __restrict__ fo2_w, const float* __restrict__ fo2_b,
    const float* __restrict__ fo3_w, const float* __restrict__ fo3_b,
    const float* __restrict__ fc1_w, const float* __restrict__ fc1_b,
    const float* __restrict__ fc2_w, const float* __restrict__ fc2_b,
    const float* __restrict__ fc3_w, const float* __restrict__ fc3_b,
    float* __restrict__ out)
{
    __shared__ __align__(16) ushort L[LDSE];

    int b = blockIdx.x, t = threadIdx.x;
    int w = t >> 6, l = t & 63, lx = l & 15, lq = l >> 4;

    // ---- xnT [64][64] (cols 48..63 zero) @ XNTP (prologue only)
    for (int i = t; i < 4096; i += 768) {
        int n = i >> 6, k = i & 63;
        float v = (k < PP) ? x[b * PP * NN + k * NN + n] * scl[k] + bia[k] : 0.f;
        L[XNTP + sidx(n, k, 64)] = f2b(v);
    }
    // ---- fr1 receiver / sender halves into BIG
    for (int i = t; i < 16384; i += 768) {
        int ch = i >> 6, k = i & 63;
        L[BIGO + sidx(ch, k, 64)]         = f2b((k < PP) ? fr1_w[ch * 96 + k] : 0.f);
        L[BIGO + 16384 + sidx(ch, k, 64)] = f2b((k < PP) ? fr1_w[ch * 96 + PP + k] : 0.f);
    }
    // ---- fr3 [64][128] -> F3LO
    for (int i = t; i < 4096; i += 768) {
        int ch = i >> 6, k2 = (i & 63) * 2;
        float2 v = *(const float2*)(fr3_w + ch * 128 + k2);
        *(unsigned*)(L + F3LO + sidx(ch, k2, 128)) = pku(v.x, v.y);
    }
    // ---- fr2 bias table -> B2LO (128 floats; REDO region is free until L3N)
    if (t < 128) ((float*)(L + B2LO))[t] = fr2_b[t];
    __syncthreads();

    // ---- GEMM1+2 fused: S1R = fr1R.xn + b1, S1S = fr1S.xn (16 m-tiles over 12 waves)
    for (int mt = w; mt < 16; mt += 12) {
        f32x4 aR[4], aS[4];
#pragma unroll
        for (int nt = 0; nt < 4; ++nt) { aR[nt] = (f32x4){0.f,0.f,0.f,0.f}; aS[nt] = (f32x4){0.f,0.f,0.f,0.f}; }
#pragma unroll
        for (int ks = 0; ks < 2; ++ks) {
            bf16x8 AfR = ldfrag(L + BIGO,         mt * 16 + lx, ks * 32 + lq * 8, 64);
            bf16x8 AfS = ldfrag(L + BIGO + 16384, mt * 16 + lx, ks * 32 + lq * 8, 64);
#pragma unroll
            for (int nt = 0; nt < 4; ++nt) {
                bf16x8 Bf = ldfrag(L + XNTP, nt * 16 + lx, ks * 32 + lq * 8, 64);
                aR[nt] = MFMA(AfR, Bf, aR[nt]);
                aS[nt] = MFMA(AfS, Bf, aS[nt]);
            }
        }
        int ch0 = mt * 16 + lq * 4;
        float4 bi = *(const float4*)(fr1_b + ch0);
        float4 zb = make_float4(0.f, 0.f, 0.f, 0.f);
#pragma unroll
        for (int nt = 0; nt < 4; ++nt) {
            stRaw(L + S1RO, nt * 16 + lx, ch0, 256, aR[nt], bi);
            stRaw(L + S1SO, nt * 16 + lx, ch0, 256, aS[nt], zb);
        }
    }
    __syncthreads();   // BIG/XNTP reads done; restage fr2 below

    // ---- fr2 [128][256] -> BIG
    for (int i = t; i < 16384; i += 768) {
        int ch = i >> 7, k2 = (i & 127) * 2;
        float2 v = *(const float2*)(fr2_w + ch * 256 + k2);
        *(unsigned*)(L + BIGO + sidx(ch, k2, 256)) = pku(v.x, v.y);
    }
    float b3c[4];
#pragma unroll
    for (int n3 = 0; n3 < 4; ++n3) b3c[n3] = fr3_b[n3 * 16 + lx];
    __syncthreads();

    // ================= phase E: receivers strided over 12 waves, zero barriers =================
    ushort* a2w = L + A2WO + w * 512;     // wave-private [16][32]
    const float* b2L = (const float*)(L + B2LO);
#pragma unroll 1
    for (int r = w; r < 64; r += 12) {
        float part[4] = {0.f, 0.f, 0.f, 0.f};
#pragma unroll 1
        for (int p = 0; p < 2; ++p) {
            int eA = p * 32 + lx, eB = eA + 16;
            int sA = eA + (eA >= r);
            int sB = eB + (eB >= r); if (sB > 63) sB = 63;   // pad edge 63

            f32x4 acc2[8][2];
#pragma unroll
            for (int m = 0; m < 8; ++m) {
                // fr2 bias from LDS table: one broadcast ds_read_b128 per m
                float4 bv = *(const float4*)(b2L + m * 16 + lq * 4);
                f32x4 bi; bi[0] = bv.x; bi[1] = bv.y; bi[2] = bv.z; bi[3] = bv.w;
                acc2[m][0] = bi; acc2[m][1] = bi;
            }
#pragma unroll
            for (int ks = 0; ks < 8; ++ks) {
                int ko = ks * 32 + lq * 8;
                U8 fr, fa, fb;
                fr.v = ldfrag(L + S1RO, r,  ko, 256);   // wave-uniform row: broadcast
                fa.v = ldfrag(L + S1SO, sA, ko, 256);
                fb.v = ldfrag(L + S1SO, sB, ko, 256);
                U8 bA, bB;
#pragma unroll
                for (int jj = 0; jj < 4; ++jj) {
                    float r0 = loF(fr.u[jj]), r1 = hiF(fr.u[jj]);
                    bA.u[jj] = pku(fmaxf(r0 + loF(fa.u[jj]), 0.f), fmaxf(r1 + hiF(fa.u[jj]), 0.f));
                    bB.u[jj] = pku(fmaxf(r0 + loF(fb.u[jj]), 0.f), fmaxf(r1 + hiF(fb.u[jj]), 0.f));
                }
#pragma unroll
                for (int m = 0; m < 8; ++m) {
                    bf16x8 Af = ldfrag(L + BIGO, m * 16 + lx, ko, 256);
                    acc2[m][0] = MFMA(Af, bA.v, acc2[m][0]);
                    acc2[m][1] = MFMA(Af, bB.v, acc2[m][1]);
                }
            }
            // ---- epilogue: fr3 GEMM through [16][32] quarters, fr3 from LDS
#pragma unroll
            for (int cc = 0; cc < 2; ++cc) {
                f32x4 acc3[4];
#pragma unroll
                for (int n3 = 0; n3 < 4; ++n3) acc3[n3] = (f32x4){0.f,0.f,0.f,0.f};
#pragma unroll
                for (int h = 0; h < 4; ++h) {
                    stAct032(a2w, lx, lq * 4,      acc2[2 * h][cc]);
                    stAct032(a2w, lx, 16 + lq * 4, acc2[2 * h + 1][cc]);
                    bf16x8 af = ldfrag32(a2w, lx, lq * 8);
#pragma unroll
                    for (int n3 = 0; n3 < 4; ++n3) {
                        bf16x8 bW = ldfrag(L + F3LO, n3 * 16 + lx, h * 32 + lq * 8, 128);
                        acc3[n3] = MFMA(af, bW, acc3[n3]);
                    }
                }
                bool mpad = (p == 1) && (cc == 1) && (lq == 3);
#pragma unroll
                for (int n3 = 0; n3 < 4; ++n3) {
                    float bv = b3c[n3];
                    float s = fmaxf(acc3[n3][0] + bv, 0.f) + fmaxf(acc3[n3][1] + bv, 0.f)
                            + fmaxf(acc3[n3][2] + bv, 0.f);
                    float s3 = fmaxf(acc3[n3][3] + bv, 0.f);
                    part[n3] += s + (mpad ? 0.f : s3);
                }
            }
        }
#pragma unroll
        for (int n3 = 0; n3 < 4; ++n3) {
            part[n3] += __shfl_xor(part[n3], 16, 64);
            part[n3] += __shfl_xor(part[n3], 32, 64);
        }
        if (lq == 0) {
#pragma unroll
            for (int n3 = 0; n3 < 4; ++n3)
                L[S1RO + sidx(r, n3 * 16 + lx, 256)] = f2b(part[n3]);
        }
    }
    __syncthreads();

    // ================= phase N =================
    // fo1 -> BIG [256][128] (cols 0..63 ebar part, 64..111 xn part)
    for (int i = t; i < 32768; i += 768) {
        int ch = i >> 7, k = i & 127;
        float v = 0.f;
        if (k < 64)       v = fo1_w[ch * 112 + PP + k];
        else if (k < 112) v = fo1_w[ch * 112 + (k - 64)];
        L[BIGO + sidx(ch, k, 128)] = f2b(v);
    }
    // xn -> S1RO cols 64..127 (48 real + 16 zero); ebar already in cols 0..63
    for (int i = t; i < 4096; i += 768) {
        int n = i >> 6, k = i & 63;
        float v = (k < PP) ? x[b * PP * NN + k * NN + n] * scl[k] + bia[k] : 0.f;
        L[S1RO + sidx(n, 64 + k, 256)] = f2b(v);
    }
    __syncthreads();

    // L1N: M=256 (16 m-tiles over 12 waves), N=64 nodes, K=128 (all from S1RO)
    for (int mt = w; mt < 16; mt += 12) {
        f32x4 accN[4];
#pragma unroll
        for (int nt = 0; nt < 4; ++nt) accN[nt] = (f32x4){0.f,0.f,0.f,0.f};
#pragma unroll
        for (int ks = 0; ks < 4; ++ks) {
            bf16x8 Af = ldfrag(L + BIGO, mt * 16 + lx, ks * 32 + lq * 8, 128);
#pragma unroll
            for (int nt = 0; nt < 4; ++nt) {
                bf16x8 Bf = ldfrag(L + S1RO, nt * 16 + lx, ks * 32 + lq * 8, 256);
                accN[nt] = MFMA(Af, Bf, accN[nt]);
            }
        }
        int ch0 = mt * 16 + lq * 4;
        float4 bi = *(const float4*)(fo1_b + ch0);
#pragma unroll
        for (int nt = 0; nt < 4; ++nt)
            stAct(L + S1SO, nt * 16 + lx, ch0, 256, accN[nt], bi);
    }
    __syncthreads();   // BIG/S1RO reads done

    // fo2 -> BIG [128][256]; fo3 -> S1RO [64][128]
    for (int i = t; i < 16384; i += 768) {
        int ch = i >> 7, k2 = (i & 127) * 2;
        float2 v = *(const float2*)(fo2_w + ch * 256 + k2);
        *(unsigned*)(L + BIGO + sidx(ch, k2, 256)) = pku(v.x, v.y);
    }
    for (int i = t; i < 4096; i += 768) {
        int ch = i >> 6, k2 = (i & 63) * 2;
        float2 v = *(const float2*)(fo3_w + ch * 128 + k2);
        *(unsigned*)(L + S1RO + sidx(ch, k2, 128)) = pku(v.x, v.y);
    }
    __syncthreads();

    // L2N: M=128 (waves 0..7), N=64, K=256 -> act2N @ F3LO [64][128]
    if (w < 8) {
        f32x4 a2N[4];
#pragma unroll
        for (int nt = 0; nt < 4; ++nt) a2N[nt] = (f32x4){0.f,0.f,0.f,0.f};
#pragma unroll
        for (int ks = 0; ks < 8; ++ks) {
            bf16x8 Af = ldfrag(L + BIGO, w * 16 + lx, ks * 32 + lq * 8, 256);
#pragma unroll
            for (int nt = 0; nt < 4; ++nt) {
                bf16x8 Bf = ldfrag(L + S1SO, nt * 16 + lx, ks * 32 + lq * 8, 256);
                a2N[nt] = MFMA(Af, Bf, a2N[nt]);
            }
        }
        int ch0 = w * 16 + lq * 4;
        float4 bi = *(const float4*)(fo2_b + ch0);
#pragma unroll
        for (int nt = 0; nt < 4; ++nt)
            stAct(L + F3LO, nt * 16 + lx, ch0, 128, a2N[nt], bi);
    }
    __syncthreads();

    // L3N: M=64 (fo3 ch), N=64 nodes, K=128 (waves 0..3); relu+bias, sum over nodes
    if (w < 4) {
        f32x4 a3N[4];
#pragma unroll
        for (int nt = 0; nt < 4; ++nt) a3N[nt] = (f32x4){0.f,0.f,0.f,0.f};
#pragma unroll
        for (int ks3 = 0; ks3 < 4; ++ks3) {
            bf16x8 Af = ldfrag(L + S1RO, 16 * w + lx, ks3 * 32 + lq * 8, 128);
#pragma unroll
            for (int nt = 0; nt < 4; ++nt) {
                bf16x8 Bf = ldfrag(L + F3LO, nt * 16 + lx, ks3 * 32 + lq * 8, 128);
                a3N[nt] = MFMA(Af, Bf, a3N[nt]);
            }
        }
        float4 b3 = *(const float4*)(fo3_b + 16 * w + lq * 4);
        float o0 = 0.f, o1 = 0.f, o2 = 0.f, o3 = 0.f;
#pragma unroll
        for (int nt = 0; nt < 4; ++nt) {
            o0 += fmaxf(a3N[nt][0] + b3.x, 0.f);
            o1 += fmaxf(a3N[nt][1] + b3.y, 0.f);
            o2 += fmaxf(a3N[nt][2] + b3.z, 0.f);
            o3 += fmaxf(a3N[nt][3] + b3.w, 0.f);
        }
#pragma unroll
        for (int off = 8; off >= 1; off >>= 1) {
            o0 += __shfl_xor(o0, off, 16);
            o1 += __shfl_xor(o1, off, 16);
            o2 += __shfl_xor(o2, off, 16);
            o3 += __shfl_xor(o3, off, 16);
        }
        if (lx == 0) {
            float* red = (float*)(L + REDO);
            *(float4*)&red[16 * w + lq * 4] = make_float4(o0, o1, o2, o3);
        }
    }
    __syncthreads();

    // ---- final FCs (fp32)
    {
        float* red = (float*)(L + REDO);
        float* h1  = red + 64;
        float* h2  = red + 96;
        if (t < 25) {
            float s = fc1_b[t];
            for (int k = 0; k < 64; ++k) s += fc1_w[t * 64 + k] * red[k];
            h1[t] = s;
        }
        __syncthreads();
        if (t < 15) {
            float s = fc2_b[t];
            for (int k = 0; k < 25; ++k) s += fc2_w[t * 25 + k] * h1[k];
            h2[t] = s;
        }
        __syncthreads();
        if (t < 5) {
            float s = fc3_b[t];
            for (int k = 0; k < 15; ++k) s += fc3_w[t * 15 + k] * h2[k];
            out[b * 5 + t] = s;
        }
    }
}

extern "C" void kernel_launch(void* const* d_in, const int* in_sizes, int n_in,
                              void* d_out, int out_size, void* d_ws, size_t ws_size,
                              hipStream_t stream)
{
    const float* x        = (const float*)d_in[0];
    const float* bn_gamma = (const float*)d_in[3];
    const float* bn_beta  = (const float*)d_in[4];
    const float* fr1_w = (const float*)d_in[5];
    const float* fr1_b = (const float*)d_in[6];
    const float* fr2_w = (const float*)d_in[7];
    const float* fr2_b = (const float*)d_in[8];
    const float* fr3_w = (const float*)d_in[9];
    const float* fr3_b = (const float*)d_in[10];
    const float* fo1_w = (const float*)d_in[11];
    const float* fo1_b = (const float*)d_in[12];
    const float* fo2_w = (const float*)d_in[13];
    const float* fo2_b = (const float*)d_in[14];
    const float* fo3_w = (const float*)d_in[15];
    const float* fo3_b = (const float*)d_in[16];
    const float* fc1_w = (const float*)d_in[17];
    const float* fc1_b = (const float*)d_in[18];
    const float* fc2_w = (const float*)d_in[19];
    const float* fc2_b = (const float*)d_in[20];
    const float* fc3_w = (const float*)d_in[21];
    const float* fc3_b = (const float*)d_in[22];

    float* ws    = (float*)d_ws;
    float* scale = ws;
    float* bias  = ws + 64;
    float* out   = (float*)d_out;

    bn_stats_kernel<<<dim3(PP), dim3(256), 0, stream>>>(x, bn_gamma, bn_beta, scale, bias);
    meg_kernel<<<dim3(BB), dim3(768), 0, stream>>>(
        x, scale, bias,
        fr1_w, fr1_b, fr2_w, fr2_b, fr3_w, fr3_b,
        fo1_w, fo1_b, fo2_w, fo2_b, fo3_w, fo3_b,
        fc1_w, fc1_b, fc2_w, fc2_b, fc3_w, fc3_b, out);
}

// Round 8
// 261.150 us; speedup vs baseline: 1.1409x; 1.0438x over previous
//
#include <hip/hip_runtime.h>
#include <hip/hip_bf16.h>

#define BB 256
#define PP 48
#define NN 64
#define EPSBN 1e-5f

typedef __attribute__((ext_vector_type(8))) short bf16x8;
typedef __attribute__((ext_vector_type(4))) float f32x4;

// ---- LDS regions (ushort offsets), total 81920 ushorts = 163840 B (160 KiB) ----
// 12-wave (768-thread) layout:
#define BIGO 0       // 32768: fr1R/[+16384]fr1S -> fr2 [128][256]   | N: fo1 [256][128] -> fo2 [128][256]
#define S1SO 32768   // 16384: S1S [64][256]                          | N: act1N [64][256]
#define S1RO 49152   // 16384: S1R [64][256]; cols 0..63 ebar; N: +xn cols 64..127 -> fo3 [64][128]
#define F3LO 65536   //  8192: fr3 [64][128] (phase E B-operand)      | N: act2N [64][128]
#define A2WO 73728   //  7680: phase E: 12 waves x 640 ([16][40] stride-40, conflict-free)
#define XNTP 73728   //  4096: prologue xnT [64][64] (aliases A2WO; dead before phase E)
#define B2LO 81408   //   256: fr2_b as 128 floats (phase E only)
#define REDO 81664   //   256: phase-N-end red/h1/h2 floats (a2w/B2LO dead by then)
#define LDSE 81920

union U8 { bf16x8 v; unsigned u[4]; };

__device__ __forceinline__ unsigned pku(float a, float b) {
    union { __hip_bfloat162 h; unsigned u; } cv;
    cv.h = __float22bfloat162_rn(make_float2(a, b));
    return cv.u;
}
__device__ __forceinline__ ushort f2b(float f) {
    union { float f; unsigned u; } a; a.f = f;
    unsigned u = a.u + 0x7FFFu + ((a.u >> 16) & 1u);
    return (ushort)(u >> 16);
}
__device__ __forceinline__ float loF(unsigned u) { union { unsigned x; float f; } c; c.x = u << 16; return c.f; }
__device__ __forceinline__ float hiF(unsigned u) { union { unsigned x; float f; } c; c.x = u & 0xffff0000u; return c.f; }

__device__ __forceinline__ int sidx(int row, int k, int kpad) {
    return row * kpad + ((((k >> 3) ^ (row & 7)) << 3) | (k & 7));
}
__device__ __forceinline__ bf16x8 ldfrag(const ushort* buf, int row, int k, int kpad) {
    return *(const bf16x8*)(buf + row * kpad + (((k >> 3) ^ (row & 7)) << 3));
}
// [16][40] wave-private buffer: odd-ish stride (80 B) spreads 16 rows over 8
// bank bases (2-way max, ~free); 16B-aligned b128 reads (80*r mod 16 == 0).
__device__ __forceinline__ bf16x8 ldfrag40(const ushort* buf, int row, int k) {
    return *(const bf16x8*)(buf + row * 40 + k);
}
__device__ __forceinline__ f32x4 MFMA(bf16x8 a, bf16x8 b, f32x4 c) {
    return __builtin_amdgcn_mfma_f32_16x16x32_bf16(a, b, c, 0, 0, 0);
}
__device__ __forceinline__ void stAct(ushort* buf, int row, int c0, int kpad, f32x4 a, float4 bi) {
    uint2 o;
    o.x = pku(fmaxf(a[0] + bi.x, 0.f), fmaxf(a[1] + bi.y, 0.f));
    o.y = pku(fmaxf(a[2] + bi.z, 0.f), fmaxf(a[3] + bi.w, 0.f));
    *(uint2*)(buf + row * kpad + ((((c0 >> 3) ^ (row & 7)) << 3) | (c0 & 7))) = o;
}
// bias folded into accumulator init: store relu(acc); stride-40 variant
__device__ __forceinline__ void stAct040(ushort* buf, int row, int c0, f32x4 a) {
    uint2 o;
    o.x = pku(fmaxf(a[0], 0.f), fmaxf(a[1], 0.f));
    o.y = pku(fmaxf(a[2], 0.f), fmaxf(a[3], 0.f));
    *(uint2*)(buf + row * 40 + c0) = o;
}
__device__ __forceinline__ void stRaw(ushort* buf, int row, int c0, int kpad, f32x4 a, float4 bi) {
    uint2 o;
    o.x = pku(a[0] + bi.x, a[1] + bi.y);
    o.y = pku(a[2] + bi.z, a[3] + bi.w);
    *(uint2*)(buf + row * kpad + ((((c0 >> 3) ^ (row & 7)) << 3) | (c0 & 7))) = o;
}

// ---------------- batchnorm stats ----------------
__global__ __launch_bounds__(256) void bn_stats_kernel(
    const float* __restrict__ x, const float* __restrict__ gamma,
    const float* __restrict__ beta, float* __restrict__ scale, float* __restrict__ bias)
{
    __shared__ float s_sum[256], s_sq[256];
    int p = blockIdx.x, t = threadIdx.x;
    float sum = 0.f, sq = 0.f;
    for (int i = t; i < BB * NN; i += 256) {
        int b = i >> 6, n = i & 63;
        float v = x[b * PP * NN + p * NN + n];
        sum += v; sq += v * v;
    }
    s_sum[t] = sum; s_sq[t] = sq;
    __syncthreads();
    for (int off = 128; off > 0; off >>= 1) {
        if (t < off) { s_sum[t] += s_sum[t + off]; s_sq[t] += s_sq[t + off]; }
        __syncthreads();
    }
    if (t == 0) {
        float inv = 1.f / (float)(BB * NN);
        float mean = s_sum[0] * inv;
        float var  = s_sq[0] * inv - mean * mean;
        float sc   = gamma[p] * rsqrtf(var + EPSBN);
        scale[p] = sc;
        bias[p]  = beta[p] - mean * sc;
    }
}

// ---------------- mega kernel: one block per batch, 12 waves (3/SIMD) ----------------
// R7: a2w re-strided [16][32]->[16][40] (4-way -> ~2-way bank conflicts on the
// epilogue round-trip, which sits on the serial acc2->acc3 chain). B2LO/REDO
// relocated to the tail to make room. Only change vs R6.
__global__ __launch_bounds__(768, 3) void meg_kernel(
    const float* __restrict__ x,
    const float* __restrict__ scl, const float* __restrict__ bia,
    const float* __restrict__ fr1_w, const float* __restrict__ fr1_b,
    const float* __restrict__ fr2_w, const float* __restrict__ fr2_b,
    const float* __restrict__ fr3_w, const float* __restrict__ fr3_b,
    const float* __restrict__ fo1_w, const float* __restrict__ fo1_b,
    const float* __restrict__ fo2_w, const float* __restrict__ fo2_b,
    const float* __restrict__ fo3_w, const float* __restrict__ fo3_b,
    const float* __restrict__ fc1_w, const float* __restrict__ fc1_b,
    const float* __restrict__ fc2_w, const float* __restrict__ fc2_b,
    const float* __restrict__ fc3_w, const float* __restrict__ fc3_b,
    float* __restrict__ out)
{
    __shared__ __align__(16) ushort L[LDSE];

    int b = blockIdx.x, t = threadIdx.x;
    int w = t >> 6, l = t & 63, lx = l & 15, lq = l >> 4;

    // ---- xnT [64][64] (cols 48..63 zero) @ XNTP (prologue only)
    for (int i = t; i < 4096; i += 768) {
        int n = i >> 6, k = i & 63;
        float v = (k < PP) ? x[b * PP * NN + k * NN + n] * scl[k] + bia[k] : 0.f;
        L[XNTP + sidx(n, k, 64)] = f2b(v);
    }
    // ---- fr1 receiver / sender halves into BIG
    for (int i = t; i < 16384; i += 768) {
        int ch = i >> 6, k = i & 63;
        L[BIGO + sidx(ch, k, 64)]         = f2b((k < PP) ? fr1_w[ch * 96 + k] : 0.f);
        L[BIGO + 16384 + sidx(ch, k, 64)] = f2b((k < PP) ? fr1_w[ch * 96 + PP + k] : 0.f);
    }
    // ---- fr3 [64][128] -> F3LO
    for (int i = t; i < 4096; i += 768) {
        int ch = i >> 6, k2 = (i & 63) * 2;
        float2 v = *(const float2*)(fr3_w + ch * 128 + k2);
        *(unsigned*)(L + F3LO + sidx(ch, k2, 128)) = pku(v.x, v.y);
    }
    // ---- fr2 bias table -> B2LO (128 floats)
    if (t < 128) ((float*)(L + B2LO))[t] = fr2_b[t];
    __syncthreads();

    // ---- GEMM1+2 fused: S1R = fr1R.xn + b1, S1S = fr1S.xn (16 m-tiles over 12 waves)
    for (int mt = w; mt < 16; mt += 12) {
        f32x4 aR[4], aS[4];
#pragma unroll
        for (int nt = 0; nt < 4; ++nt) { aR[nt] = (f32x4){0.f,0.f,0.f,0.f}; aS[nt] = (f32x4){0.f,0.f,0.f,0.f}; }
#pragma unroll
        for (int ks = 0; ks < 2; ++ks) {
            bf16x8 AfR = ldfrag(L + BIGO,         mt * 16 + lx, ks * 32 + lq * 8, 64);
            bf16x8 AfS = ldfrag(L + BIGO + 16384, mt * 16 + lx, ks * 32 + lq * 8, 64);
#pragma unroll
            for (int nt = 0; nt < 4; ++nt) {
                bf16x8 Bf = ldfrag(L + XNTP, nt * 16 + lx, ks * 32 + lq * 8, 64);
                aR[nt] = MFMA(AfR, Bf, aR[nt]);
                aS[nt] = MFMA(AfS, Bf, aS[nt]);
            }
        }
        int ch0 = mt * 16 + lq * 4;
        float4 bi = *(const float4*)(fr1_b + ch0);
        float4 zb = make_float4(0.f, 0.f, 0.f, 0.f);
#pragma unroll
        for (int nt = 0; nt < 4; ++nt) {
            stRaw(L + S1RO, nt * 16 + lx, ch0, 256, aR[nt], bi);
            stRaw(L + S1SO, nt * 16 + lx, ch0, 256, aS[nt], zb);
        }
    }
    __syncthreads();   // BIG/XNTP reads done; restage fr2 below

    // ---- fr2 [128][256] -> BIG
    for (int i = t; i < 16384; i += 768) {
        int ch = i >> 7, k2 = (i & 127) * 2;
        float2 v = *(const float2*)(fr2_w + ch * 256 + k2);
        *(unsigned*)(L + BIGO + sidx(ch, k2, 256)) = pku(v.x, v.y);
    }
    float b3c[4];
#pragma unroll
    for (int n3 = 0; n3 < 4; ++n3) b3c[n3] = fr3_b[n3 * 16 + lx];
    __syncthreads();

    // ================= phase E: receivers strided over 12 waves, zero barriers =================
    ushort* a2w = L + A2WO + w * 640;     // wave-private [16][40]
    const float* b2L = (const float*)(L + B2LO);
#pragma unroll 1
    for (int r = w; r < 64; r += 12) {
        float part[4] = {0.f, 0.f, 0.f, 0.f};
#pragma unroll 1
        for (int p = 0; p < 2; ++p) {
            int eA = p * 32 + lx, eB = eA + 16;
            int sA = eA + (eA >= r);
            int sB = eB + (eB >= r); if (sB > 63) sB = 63;   // pad edge 63

            f32x4 acc2[8][2];
#pragma unroll
            for (int m = 0; m < 8; ++m) {
                // fr2 bias from LDS table: one broadcast read per m
                float4 bv = *(const float4*)(b2L + m * 16 + lq * 4);
                f32x4 bi; bi[0] = bv.x; bi[1] = bv.y; bi[2] = bv.z; bi[3] = bv.w;
                acc2[m][0] = bi; acc2[m][1] = bi;
            }
#pragma unroll
            for (int ks = 0; ks < 8; ++ks) {
                int ko = ks * 32 + lq * 8;
                U8 fr, fa, fb;
                fr.v = ldfrag(L + S1RO, r,  ko, 256);   // wave-uniform row: broadcast
                fa.v = ldfrag(L + S1SO, sA, ko, 256);
                fb.v = ldfrag(L + S1SO, sB, ko, 256);
                U8 bA, bB;
#pragma unroll
                for (int jj = 0; jj < 4; ++jj) {
                    float r0 = loF(fr.u[jj]), r1 = hiF(fr.u[jj]);
                    bA.u[jj] = pku(fmaxf(r0 + loF(fa.u[jj]), 0.f), fmaxf(r1 + hiF(fa.u[jj]), 0.f));
                    bB.u[jj] = pku(fmaxf(r0 + loF(fb.u[jj]), 0.f), fmaxf(r1 + hiF(fb.u[jj]), 0.f));
                }
#pragma unroll
                for (int m = 0; m < 8; ++m) {
                    bf16x8 Af = ldfrag(L + BIGO, m * 16 + lx, ko, 256);
                    acc2[m][0] = MFMA(Af, bA.v, acc2[m][0]);
                    acc2[m][1] = MFMA(Af, bB.v, acc2[m][1]);
                }
            }
            // ---- epilogue: fr3 GEMM through [16][40] quarters, fr3 from LDS
#pragma unroll
            for (int cc = 0; cc < 2; ++cc) {
                f32x4 acc3[4];
#pragma unroll
                for (int n3 = 0; n3 < 4; ++n3) acc3[n3] = (f32x4){0.f,0.f,0.f,0.f};
#pragma unroll
                for (int h = 0; h < 4; ++h) {
                    stAct040(a2w, lx, lq * 4,      acc2[2 * h][cc]);
                    stAct040(a2w, lx, 16 + lq * 4, acc2[2 * h + 1][cc]);
                    bf16x8 af = ldfrag40(a2w, lx, lq * 8);
#pragma unroll
                    for (int n3 = 0; n3 < 4; ++n3) {
                        bf16x8 bW = ldfrag(L + F3LO, n3 * 16 + lx, h * 32 + lq * 8, 128);
                        acc3[n3] = MFMA(af, bW, acc3[n3]);
                    }
                }
                bool mpad = (p == 1) && (cc == 1) && (lq == 3);
#pragma unroll
                for (int n3 = 0; n3 < 4; ++n3) {
                    float bv = b3c[n3];
                    float s = fmaxf(acc3[n3][0] + bv, 0.f) + fmaxf(acc3[n3][1] + bv, 0.f)
                            + fmaxf(acc3[n3][2] + bv, 0.f);
                    float s3 = fmaxf(acc3[n3][3] + bv, 0.f);
                    part[n3] += s + (mpad ? 0.f : s3);
                }
            }
        }
#pragma unroll
        for (int n3 = 0; n3 < 4; ++n3) {
            part[n3] += __shfl_xor(part[n3], 16, 64);
            part[n3] += __shfl_xor(part[n3], 32, 64);
        }
        if (lq == 0) {
#pragma unroll
            for (int n3 = 0; n3 < 4; ++n3)
                L[S1RO + sidx(r, n3 * 16 + lx, 256)] = f2b(part[n3]);
        }
    }
    __syncthreads();

    // ================= phase N =================
    // fo1 -> BIG [256][128] (cols 0..63 ebar part, 64..111 xn part)
    for (int i = t; i < 32768; i += 768) {
        int ch = i >> 7, k = i & 127;
        float v = 0.f;
        if (k < 64)       v = fo1_w[ch * 112 + PP + k];
        else if (k < 112) v = fo1_w[ch * 112 + (k - 64)];
        L[BIGO + sidx(ch, k, 128)] = f2b(v);
    }
    // xn -> S1RO cols 64..127 (48 real + 16 zero); ebar already in cols 0..63
    for (int i = t; i < 4096; i += 768) {
        int n = i >> 6, k = i & 63;
        float v = (k < PP) ? x[b * PP * NN + k * NN + n] * scl[k] + bia[k] : 0.f;
        L[S1RO + sidx(n, 64 + k, 256)] = f2b(v);
    }
    __syncthreads();

    // L1N: M=256 (16 m-tiles over 12 waves), N=64 nodes, K=128 (all from S1RO)
    for (int mt = w; mt < 16; mt += 12) {
        f32x4 accN[4];
#pragma unroll
        for (int nt = 0; nt < 4; ++nt) accN[nt] = (f32x4){0.f,0.f,0.f,0.f};
#pragma unroll
        for (int ks = 0; ks < 4; ++ks) {
            bf16x8 Af = ldfrag(L + BIGO, mt * 16 + lx, ks * 32 + lq * 8, 128);
#pragma unroll
            for (int nt = 0; nt < 4; ++nt) {
                bf16x8 Bf = ldfrag(L + S1RO, nt * 16 + lx, ks * 32 + lq * 8, 256);
                accN[nt] = MFMA(Af, Bf, accN[nt]);
            }
        }
        int ch0 = mt * 16 + lq * 4;
        float4 bi = *(const float4*)(fo1_b + ch0);
#pragma unroll
        for (int nt = 0; nt < 4; ++nt)
            stAct(L + S1SO, nt * 16 + lx, ch0, 256, accN[nt], bi);
    }
    __syncthreads();   // BIG/S1RO reads done

    // fo2 -> BIG [128][256]; fo3 -> S1RO [64][128]
    for (int i = t; i < 16384; i += 768) {
        int ch = i >> 7, k2 = (i & 127) * 2;
        float2 v = *(const float2*)(fo2_w + ch * 256 + k2);
        *(unsigned*)(L + BIGO + sidx(ch, k2, 256)) = pku(v.x, v.y);
    }
    for (int i = t; i < 4096; i += 768) {
        int ch = i >> 6, k2 = (i & 63) * 2;
        float2 v = *(const float2*)(fo3_w + ch * 128 + k2);
        *(unsigned*)(L + S1RO + sidx(ch, k2, 128)) = pku(v.x, v.y);
    }
    __syncthreads();

    // L2N: M=128 (waves 0..7), N=64, K=256 -> act2N @ F3LO [64][128]
    if (w < 8) {
        f32x4 a2N[4];
#pragma unroll
        for (int nt = 0; nt < 4; ++nt) a2N[nt] = (f32x4){0.f,0.f,0.f,0.f};
#pragma unroll
        for (int ks = 0; ks < 8; ++ks) {
            bf16x8 Af = ldfrag(L + BIGO, w * 16 + lx, ks * 32 + lq * 8, 256);
#pragma unroll
            for (int nt = 0; nt < 4; ++nt) {
                bf16x8 Bf = ldfrag(L + S1SO, nt * 16 + lx, ks * 32 + lq * 8, 256);
                a2N[nt] = MFMA(Af, Bf, a2N[nt]);
            }
        }
        int ch0 = w * 16 + lq * 4;
        float4 bi = *(const float4*)(fo2_b + ch0);
#pragma unroll
        for (int nt = 0; nt < 4; ++nt)
            stAct(L + F3LO, nt * 16 + lx, ch0, 128, a2N[nt], bi);
    }
    __syncthreads();

    // L3N: M=64 (fo3 ch), N=64 nodes, K=128 (waves 0..3); relu+bias, sum over nodes
    if (w < 4) {
        f32x4 a3N[4];
#pragma unroll
        for (int nt = 0; nt < 4; ++nt) a3N[nt] = (f32x4){0.f,0.f,0.f,0.f};
#pragma unroll
        for (int ks3 = 0; ks3 < 4; ++ks3) {
            bf16x8 Af = ldfrag(L + S1RO, 16 * w + lx, ks3 * 32 + lq * 8, 128);
#pragma unroll
            for (int nt = 0; nt < 4; ++nt) {
                bf16x8 Bf = ldfrag(L + F3LO, nt * 16 + lx, ks3 * 32 + lq * 8, 128);
                a3N[nt] = MFMA(Af, Bf, a3N[nt]);
            }
        }
        float4 b3 = *(const float4*)(fo3_b + 16 * w + lq * 4);
        float o0 = 0.f, o1 = 0.f, o2 = 0.f, o3 = 0.f;
#pragma unroll
        for (int nt = 0; nt < 4; ++nt) {
            o0 += fmaxf(a3N[nt][0] + b3.x, 0.f);
            o1 += fmaxf(a3N[nt][1] + b3.y, 0.f);
            o2 += fmaxf(a3N[nt][2] + b3.z, 0.f);
            o3 += fmaxf(a3N[nt][3] + b3.w, 0.f);
        }
#pragma unroll
        for (int off = 8; off >= 1; off >>= 1) {
            o0 += __shfl_xor(o0, off, 16);
            o1 += __shfl_xor(o1, off, 16);
            o2 += __shfl_xor(o2, off, 16);
            o3 += __shfl_xor(o3, off, 16);
        }
        if (lx == 0) {
            float* red = (float*)(L + REDO);
            *(float4*)&red[16 * w + lq * 4] = make_float4(o0, o1, o2, o3);
        }
    }
    __syncthreads();

    // ---- final FCs (fp32)
    {
        float* red = (float*)(L + REDO);
        float* h1  = red + 64;
        float* h2  = red + 96;
        if (t < 25) {
            float s = fc1_b[t];
            for (int k = 0; k < 64; ++k) s += fc1_w[t * 64 + k] * red[k];
            h1[t] = s;
        }
        __syncthreads();
        if (t < 15) {
            float s = fc2_b[t];
            for (int k = 0; k < 25; ++k) s += fc2_w[t * 25 + k] * h1[k];
            h2[t] = s;
        }
        __syncthreads();
        if (t < 5) {
            float s = fc3_b[t];
            for (int k = 0; k < 15; ++k) s += fc3_w[t * 15 + k] * h2[k];
            out[b * 5 + t] = s;
        }
    }
}

extern "C" void kernel_launch(void* const* d_in, const int* in_sizes, int n_in,
                              void* d_out, int out_size, void* d_ws, size_t ws_size,
                              hipStream_t stream)
{
    const float* x        = (const float*)d_in[0];
    const float* bn_gamma = (const float*)d_in[3];
    const float* bn_beta  = (const float*)d_in[4];
    const float* fr1_w = (const float*)d_in[5];
    const float* fr1_b = (const float*)d_in[6];
    const float* fr2_w = (const float*)d_in[7];
    const float* fr2_b = (const float*)d_in[8];
    const float* fr3_w = (const float*)d_in[9];
    const float* fr3_b = (const float*)d_in[10];
    const float* fo1_w = (const float*)d_in[11];
    const float* fo1_b = (const float*)d_in[12];
    const float* fo2_w = (const float*)d_in[13];
    const float* fo2_b = (const float*)d_in[14];
    const float* fo3_w = (const float*)d_in[15];
    const float* fo3_b = (const float*)d_in[16];
    const float* fc1_w = (const float*)d_in[17];
    const float* fc1_b = (const float*)d_in[18];
    const float* fc2_w = (const float*)d_in[19];
    const float* fc2_b = (const float*)d_in[20];
    const float* fc3_w = (const float*)d_in[21];
    const float* fc3_b = (const float*)d_in[22];

    float* ws    = (float*)d_ws;
    float* scale = ws;
    float* bias  = ws + 64;
    float* out   = (float*)d_out;

    bn_stats_kernel<<<dim3(PP), dim3(256), 0, stream>>>(x, bn_gamma, bn_beta, scale, bias);
    meg_kernel<<<dim3(BB), dim3(768), 0, stream>>>(
        x, scale, bias,
        fr1_w, fr1_b, fr2_w, fr2_b, fr3_w, fr3_b,
        fo1_w, fo1_b, fo2_w, fo2_b, fo3_w, fo3_b,
        fc1_w, fc1_b, fc2_w, fc2_b, fc3_w, fc3_b, out);
}